// Round 7
// baseline (21.347 us; speedup 1.0000x reference)
//
#include <hip/hip_runtime.h>
#include <math.h>

#define NP 5
#define NH 64
#define BLK 256
#define SPB 128   // samples per block; 2 waves (k-halves) per 64-sample group

typedef float f32x2 __attribute__((ext_vector_type(2)));

#define LOG2E 1.44269504088896340736f
// -2y(z)*log2(e) = z*(-C_CDF0 - C_CDF1*z^2),  2y = 1.5957691*(z + 0.044715 z^3)
#define C_CDF0 2.30220840f
#define C_CDF1 0.10294324f
// d(2y)/dz = C_G2A + C_G2B*z^2
#define C_G2A 1.59576912f
#define C_G2B 0.21406460f
// phi(z)=exp2(C_PDF_A*z^2 + C_PDF_B)  (exact Gaussian, 1/sqrt(2pi) folded)
#define C_PDF_A (-0.72134752f)
#define C_PDF_B (-1.32574806f)

__global__ __launch_bounds__(BLK, 6) void topo_kernel(
    const float* __restrict__ pillars,
    const float* __restrict__ gW1,   // [5][64]
    const float* __restrict__ gb1,   // [64]
    const float* __restrict__ gW2,   // [64]
    const float* __restrict__ gb2,   // [1]
    const float* __restrict__ gLng,  // [5]
    const float* __restrict__ gLnb,  // [5]
    const float* __restrict__ gWc,   // [12]
    const float* __restrict__ gbc,   // [1]
    float* __restrict__ out,
    int n)
{
    __shared__ float sRed[SPB * 8];   // padded stride-8, 4KB

    const int t    = threadIdx.x;
    const int lane = t & 63;
    const int wid  = __builtin_amdgcn_readfirstlane(t >> 6);  // wave-uniform
    const int half = wid & 1;         // which 32-unit half this wave computes
    const int sgrp = wid >> 1;        // which 64-sample group
    const int sloc = sgrp * 64 + lane;            // 0..127 within block
    long sample = (long)blockIdx.x * SPB + sloc;
    const bool valid = sample < n;
    if (!valid) sample = n - 1;       // clamp loads; store is guarded

    // LN constants (uniform scalar loads)
    float gam[NP], bet[NP];
    #pragma unroll
    for (int j = 0; j < NP; ++j) { gam[j] = gLng[j]; bet[j] = gLnb[j]; }

    const float* prow = pillars + sample * NP;
    float raw[NP], p[NP], x[NP];
    #pragma unroll
    for (int j = 0; j < NP; ++j) raw[j] = prow[j];

    float mu = 0.f;
    #pragma unroll
    for (int j = 0; j < NP; ++j) {
        float v = raw[j];
        if (!(v == v)) v = 0.5f;          // NaN -> 0.5
        v = fminf(fmaxf(v, 0.f), 1.f);    // clip (handles +/-inf)
        p[j] = v; mu += v;
    }
    mu *= 0.2f;
    float var = 0.f;
    #pragma unroll
    for (int j = 0; j < NP; ++j) { float d = p[j] - mu; var += d * d; }
    var *= 0.2f;
    float inv = rsqrtf(var + 1e-5f);
    #pragma unroll
    for (int j = 0; j < NP; ++j) x[j] = (p[j] - mu) * inv * gam[j] + bet[j];

    // this wave's unit-half: elements [half*32, half*32+32)
    const int kb = half * 32;
    const float* w0p = gW1 + 0*NH + kb;
    const float* w1p = gW1 + 1*NH + kb;
    const float* w2p = gW1 + 2*NH + kb;
    const float* w3p = gW1 + 3*NH + kb;
    const float* w4p = gW1 + 4*NH + kb;
    const float* bbp = gb1 + kb;
    const float* wop = gW2 + kb;

    const f32x2 one = {1.f, 1.f};
    const f32x2 cC0 = {-C_CDF0, -C_CDF0}, cC1 = {-C_CDF1, -C_CDF1};
    const f32x2 cGA = {C_G2A, C_G2A},     cGB = {C_G2B, C_G2B};

    // ---------------- pass A: z-side (V, grad) -- needs P splats only ------
    float pv, pg0, pg1, pg2, pg3, pg4;
    {
        f32x2 P0 = {p[0],p[0]}, P1 = {p[1],p[1]}, P2 = {p[2],p[2]},
              P3 = {p[3],p[3]}, P4 = {p[4],p[4]};
        f32x2 V2 = {0.f,0.f};
        f32x2 G0 = {0.f,0.f}, G1 = {0.f,0.f}, G2 = {0.f,0.f},
              G3 = {0.f,0.f}, G4 = {0.f,0.f};
        #pragma unroll 4
        for (int pp = 0; pp < 16; ++pp) {
            const int k0 = 2 * pp;
            f32x2 w0 = {w0p[k0], w0p[k0 + 1]};
            f32x2 w1 = {w1p[k0], w1p[k0 + 1]};
            f32x2 w2 = {w2p[k0], w2p[k0 + 1]};
            f32x2 w3 = {w3p[k0], w3p[k0 + 1]};
            f32x2 w4 = {w4p[k0], w4p[k0 + 1]};
            f32x2 bb = {bbp[k0], bbp[k0 + 1]};
            f32x2 wo = {wop[k0], wop[k0 + 1]};

            f32x2 z  = (P0*w0 + P1*w1) + (P2*w2 + P3*w3) + (P4*w4 + bb);
            f32x2 tz = z * z;
            f32x2 ya = z * (tz * cC1 + cC0);
            f32x2 e;
            e.x = __builtin_amdgcn_exp2f(ya.x);
            e.y = __builtin_amdgcn_exp2f(ya.y);
            f32x2 ope = e + one;
            f32x2 s;
            s.x = __builtin_amdgcn_rcpf(ope.x);
            s.y = __builtin_amdgcn_rcpf(ope.y);

            V2 = (z * s) * wo + V2;                       // gelu(z)*W2
            f32x2 u   = s - s * s;                        // sigma*(1-sigma)
            f32x2 g2p = tz * cGB + cGA;                   // d(2y)/dz
            f32x2 d1  = ((z * u) * g2p + s) * wo;         // gelu'(z)*W2
            G0 = w0 * d1 + G0; G1 = w1 * d1 + G1; G2 = w2 * d1 + G2;
            G3 = w3 * d1 + G3; G4 = w4 * d1 + G4;
        }
        pv  = V2.x + V2.y;
        pg0 = G0.x + G0.y; pg1 = G1.x + G1.y; pg2 = G2.x + G2.y;
        pg3 = G3.x + G3.y; pg4 = G4.x + G4.y;
    }

    // ---------------- pass B: zx-side (trace) -- needs X splats only -------
    float ptr;
    {
        f32x2 X0 = {x[0],x[0]}, X1 = {x[1],x[1]}, X2 = {x[2],x[2]},
              X3 = {x[3],x[3]}, X4 = {x[4],x[4]};
        const f32x2 two = {2.f, 2.f};
        const f32x2 cPA = {C_PDF_A, C_PDF_A}, cPB = {C_PDF_B, C_PDF_B};
        f32x2 TR = {0.f,0.f};
        #pragma unroll 4
        for (int pp = 0; pp < 16; ++pp) {
            const int k0 = 2 * pp;
            f32x2 w0 = {w0p[k0], w0p[k0 + 1]};
            f32x2 w1 = {w1p[k0], w1p[k0 + 1]};
            f32x2 w2 = {w2p[k0], w2p[k0 + 1]};
            f32x2 w3 = {w3p[k0], w3p[k0 + 1]};
            f32x2 w4 = {w4p[k0], w4p[k0 + 1]};
            f32x2 bb = {bbp[k0], bbp[k0 + 1]};
            f32x2 wo = {wop[k0], wop[k0 + 1]};

            f32x2 ssum = (w0*w0 + w1*w1) + (w2*w2 + w3*w3) + w4*w4;
            f32x2 sw = ssum * wo;

            f32x2 zx = (X0*w0 + X1*w1) + (X2*w2 + X3*w3) + (X4*w4 + bb);
            f32x2 tx = zx * zx;
            f32x2 pa = tx * cPA + cPB;
            f32x2 ph;
            ph.x = __builtin_amdgcn_exp2f(pa.x);
            ph.y = __builtin_amdgcn_exp2f(pa.y);
            TR = (sw * (two - tx)) * ph + TR;
        }
        ptr = TR.x + TR.y;
    }

    // ---------------- combine halves via LDS -------------------------------
    if (half) {
        float* r = &sRed[sloc * 8];
        r[0] = pv; r[1] = ptr; r[2] = pg0; r[3] = pg1;
        r[4] = pg2; r[5] = pg3; r[6] = pg4;
    }
    __syncthreads();
    if (half) return;

    {
        const float* r = &sRed[sloc * 8];
        pv  += r[0]; ptr += r[1];
        pg0 += r[2]; pg1 += r[3]; pg2 += r[4]; pg3 += r[5]; pg4 += r[6];
    }

    float wcf[12];
    #pragma unroll
    for (int i = 0; i < 12; ++i) wcf[i] = gWc[i];
    const float b2v = gb2[0], bcv = gbc[0];

    float V = pv + b2v;
    float emean = 0.2f * ptr;

    float f[12];
    f[0] = raw[0]; f[1] = raw[1]; f[2] = raw[2]; f[3] = raw[3]; f[4] = raw[4];
    f[5] = pg0; f[6] = pg1; f[7] = pg2; f[8] = pg3; f[9] = pg4;
    f[10] = V; f[11] = emean;

    float nrm = 0.f;
    #pragma unroll
    for (int i = 0; i < 12; ++i) nrm = fmaf(f[i], f[i], nrm);
    float denom = fmaxf(sqrtf(nrm), 1e-12f);
    float dot = 0.f;
    #pragma unroll
    for (int i = 0; i < 12; ++i) dot = fmaf(f[i], wcf[i], dot);
    float sarg = dot * __builtin_amdgcn_rcpf(denom) + bcv;
    float es = __builtin_amdgcn_exp2f(-sarg * LOG2E);
    float prob = __builtin_amdgcn_rcpf(1.0f + es);
    prob = fminf(fmaxf(prob, 0.f), 1.f);
    if (valid) out[sample] = prob;
}

extern "C" void kernel_launch(void* const* d_in, const int* in_sizes, int n_in,
                              void* d_out, int out_size, void* d_ws, size_t ws_size,
                              hipStream_t stream) {
    const float* pillars = (const float*)d_in[0];
    const float* W1  = (const float*)d_in[1];
    const float* b1  = (const float*)d_in[2];
    const float* W2  = (const float*)d_in[3];
    const float* b2  = (const float*)d_in[4];
    const float* lng = (const float*)d_in[5];
    const float* lnb = (const float*)d_in[6];
    const float* Wc  = (const float*)d_in[7];
    const float* bc  = (const float*)d_in[8];
    float* out = (float*)d_out;

    const int n = in_sizes[0] / NP;     // 262144
    const int blocks = (n + SPB - 1) / SPB;   // 2048 blocks, 8192 waves
    topo_kernel<<<blocks, BLK, 0, stream>>>(
        pillars, W1, b1, W2, b2, lng, lnb, Wc, bc, out, n);
}

// Round 8
// 20.010 us; speedup vs baseline: 1.0668x; 1.0668x over previous
//
#include <hip/hip_runtime.h>
#include <math.h>

#define NP 5
#define NH 64
#define BLK 256

typedef float f32x2 __attribute__((ext_vector_type(2)));

#define LOG2E 1.44269504088896340736f
// -2y(z)*log2(e) = z*(-C_CDF0 - C_CDF1*z^2),  2y = 1.5957691*(z + 0.044715 z^3)
#define C_CDF0 2.30220840f
#define C_CDF1 0.10294324f
// d(2y)/dz = C_G2A + C_G2B*z^2
#define C_G2A 1.59576912f
#define C_G2B 0.21406460f
// phi(z)=exp2(C_PDF_A*z^2 + C_PDF_B)  (exact Gaussian, 1/sqrt(2pi) folded)
#define C_PDF_A (-0.72134752f)
#define C_PDF_B (-1.32574806f)

__global__ void topo_kernel(
    const float* __restrict__ pillars,
    const float* __restrict__ gW1,   // [5][64]
    const float* __restrict__ gb1,   // [64]
    const float* __restrict__ gW2,   // [64]
    const float* __restrict__ gb2,   // [1]
    const float* __restrict__ gLng,  // [5]
    const float* __restrict__ gLnb,  // [5]
    const float* __restrict__ gWc,   // [12]
    const float* __restrict__ gbc,   // [1]
    float* __restrict__ out,
    int n)
{
    const int t = threadIdx.x;
    const int half_n = n >> 1;                     // n = 262144, even
    const long sA = (long)blockIdx.x * BLK + t;    // first sample
    const long sB = sA + half_n;                   // second sample
    if (sA >= half_n) return;

    // LN constants (uniform scalar loads)
    float gam[NP], bet[NP];
    #pragma unroll
    for (int j = 0; j < NP; ++j) { gam[j] = gLng[j]; bet[j] = gLnb[j]; }

    // ---- per-sample preamble (done for A and B) ----
    float rawA[NP], rawB[NP], pA[NP], pB[NP], xA[NP], xB[NP];
    {
        const float* prA = pillars + sA * NP;
        const float* prB = pillars + sB * NP;
        #pragma unroll
        for (int j = 0; j < NP; ++j) { rawA[j] = prA[j]; rawB[j] = prB[j]; }
    }
#define PREP(raw, pp_, xx_)                                                  \
    do {                                                                     \
        float mu = 0.f;                                                      \
        _Pragma("unroll")                                                    \
        for (int j = 0; j < NP; ++j) {                                       \
            float v = raw[j];                                                \
            if (!(v == v)) v = 0.5f;                                         \
            v = fminf(fmaxf(v, 0.f), 1.f);                                   \
            pp_[j] = v; mu += v;                                             \
        }                                                                    \
        mu *= 0.2f;                                                          \
        float var = 0.f;                                                     \
        _Pragma("unroll")                                                    \
        for (int j = 0; j < NP; ++j) { float d = pp_[j] - mu; var += d * d; }\
        var *= 0.2f;                                                         \
        float inv = rsqrtf(var + 1e-5f);                                     \
        _Pragma("unroll")                                                    \
        for (int j = 0; j < NP; ++j)                                         \
            xx_[j] = (pp_[j] - mu) * inv * gam[j] + bet[j];                  \
    } while (0)
    PREP(rawA, pA, xA);
    PREP(rawB, pB, xB);
#undef PREP

    f32x2 PA[NP], XA[NP], PB[NP], XB[NP];
    #pragma unroll
    for (int j = 0; j < NP; ++j) {
        PA[j] = (f32x2){pA[j], pA[j]}; XA[j] = (f32x2){xA[j], xA[j]};
        PB[j] = (f32x2){pB[j], pB[j]}; XB[j] = (f32x2){xB[j], xB[j]};
    }

    const f32x2 one = {1.f, 1.f}, two = {2.f, 2.f};
    const f32x2 cC0 = {-C_CDF0, -C_CDF0}, cC1 = {-C_CDF1, -C_CDF1};
    const f32x2 cGA = {C_G2A, C_G2A},     cGB = {C_G2B, C_G2B};
    const f32x2 cPA = {C_PDF_A, C_PDF_A}, cPB = {C_PDF_B, C_PDF_B};

    f32x2 VA = {0.f,0.f}, TRA = {0.f,0.f};
    f32x2 GA0 = {0.f,0.f}, GA1 = {0.f,0.f}, GA2 = {0.f,0.f}, GA3 = {0.f,0.f}, GA4 = {0.f,0.f};
    f32x2 VB = {0.f,0.f}, TRB = {0.f,0.f};
    f32x2 GB0 = {0.f,0.f}, GB1 = {0.f,0.f}, GB2 = {0.f,0.f}, GB3 = {0.f,0.f}, GB4 = {0.f,0.f};

// per-pair body for one sample, weights w0..w4,bb,wo,sw in scope
#define PAIR(P, X, V2, TR, G0, G1, G2, G3, G4)                               \
    do {                                                                     \
        f32x2 z  = (P[0]*w0 + P[1]*w1) + (P[2]*w2 + P[3]*w3) + (P[4]*w4 + bb); \
        f32x2 zx = (X[0]*w0 + X[1]*w1) + (X[2]*w2 + X[3]*w3) + (X[4]*w4 + bb); \
        f32x2 tz = z * z;                                                    \
        f32x2 tx = zx * zx;                                                  \
        f32x2 ya = z * (tz * cC1 + cC0);                                     \
        f32x2 e;                                                             \
        e.x = __builtin_amdgcn_exp2f(ya.x);                                  \
        e.y = __builtin_amdgcn_exp2f(ya.y);                                  \
        f32x2 ope = e + one;                                                 \
        f32x2 s;                                                             \
        s.x = __builtin_amdgcn_rcpf(ope.x);                                  \
        s.y = __builtin_amdgcn_rcpf(ope.y);                                  \
        V2 = (z * s) * wo + V2;                                              \
        f32x2 u   = s - s * s;                                               \
        f32x2 g2p = tz * cGB + cGA;                                          \
        f32x2 d1  = ((z * u) * g2p + s) * wo;                                \
        G0 = w0 * d1 + G0; G1 = w1 * d1 + G1; G2 = w2 * d1 + G2;             \
        G3 = w3 * d1 + G3; G4 = w4 * d1 + G4;                                \
        f32x2 pa = tx * cPA + cPB;                                           \
        f32x2 ph;                                                            \
        ph.x = __builtin_amdgcn_exp2f(pa.x);                                 \
        ph.y = __builtin_amdgcn_exp2f(pa.y);                                 \
        TR = (sw * (two - tx)) * ph + TR;                                    \
    } while (0)

    #pragma unroll 4
    for (int pp = 0; pp < 32; ++pp) {
        const int k0 = 2 * pp;
        f32x2 w0 = {gW1[0*NH + k0], gW1[0*NH + k0 + 1]};
        f32x2 w1 = {gW1[1*NH + k0], gW1[1*NH + k0 + 1]};
        f32x2 w2 = {gW1[2*NH + k0], gW1[2*NH + k0 + 1]};
        f32x2 w3 = {gW1[3*NH + k0], gW1[3*NH + k0 + 1]};
        f32x2 w4 = {gW1[4*NH + k0], gW1[4*NH + k0 + 1]};
        f32x2 bb = {gb1[k0], gb1[k0 + 1]};
        f32x2 wo = {gW2[k0], gW2[k0 + 1]};

        // sw = (sum_j w_j^2) * wo   (0.2 folded into epilogue)
        f32x2 ssum = (w0*w0 + w1*w1) + (w2*w2 + w3*w3) + w4*w4;
        f32x2 sw = ssum * wo;

        PAIR(PA, XA, VA, TRA, GA0, GA1, GA2, GA3, GA4);
        PAIR(PB, XB, VB, TRB, GB0, GB1, GB2, GB3, GB4);
    }
#undef PAIR

    float wcf[12];
    #pragma unroll
    for (int i = 0; i < 12; ++i) wcf[i] = gWc[i];
    const float b2v = gb2[0], bcv = gbc[0];

#define EPILOG(raw, V2, TR, G0, G1, G2, G3, G4, sidx)                        \
    do {                                                                     \
        float V = V2.x + V2.y + b2v;                                         \
        float emean = 0.2f * (TR.x + TR.y);                                  \
        float f[12];                                                         \
        f[0] = raw[0]; f[1] = raw[1]; f[2] = raw[2]; f[3] = raw[3]; f[4] = raw[4]; \
        f[5] = G0.x + G0.y; f[6] = G1.x + G1.y; f[7] = G2.x + G2.y;          \
        f[8] = G3.x + G3.y; f[9] = G4.x + G4.y;                              \
        f[10] = V; f[11] = emean;                                            \
        float nrm = 0.f;                                                     \
        _Pragma("unroll")                                                    \
        for (int i = 0; i < 12; ++i) nrm = fmaf(f[i], f[i], nrm);            \
        float denom = fmaxf(sqrtf(nrm), 1e-12f);                             \
        float dot = 0.f;                                                     \
        _Pragma("unroll")                                                    \
        for (int i = 0; i < 12; ++i) dot = fmaf(f[i], wcf[i], dot);          \
        float sarg = dot * __builtin_amdgcn_rcpf(denom) + bcv;               \
        float es = __builtin_amdgcn_exp2f(-sarg * LOG2E);                    \
        float prob = __builtin_amdgcn_rcpf(1.0f + es);                       \
        prob = fminf(fmaxf(prob, 0.f), 1.f);                                 \
        out[sidx] = prob;                                                    \
    } while (0)

    EPILOG(rawA, VA, TRA, GA0, GA1, GA2, GA3, GA4, sA);
    EPILOG(rawB, VB, TRB, GB0, GB1, GB2, GB3, GB4, sB);
#undef EPILOG
}

extern "C" void kernel_launch(void* const* d_in, const int* in_sizes, int n_in,
                              void* d_out, int out_size, void* d_ws, size_t ws_size,
                              hipStream_t stream) {
    const float* pillars = (const float*)d_in[0];
    const float* W1  = (const float*)d_in[1];
    const float* b1  = (const float*)d_in[2];
    const float* W2  = (const float*)d_in[3];
    const float* b2  = (const float*)d_in[4];
    const float* lng = (const float*)d_in[5];
    const float* lnb = (const float*)d_in[6];
    const float* Wc  = (const float*)d_in[7];
    const float* bc  = (const float*)d_in[8];
    float* out = (float*)d_out;

    const int n = in_sizes[0] / NP;     // 262144
    const int half_n = n >> 1;          // 2 samples per thread
    const int blocks = (half_n + BLK - 1) / BLK;   // 512
    topo_kernel<<<blocks, BLK, 0, stream>>>(
        pillars, W1, b1, W2, b2, lng, lnb, Wc, bc, out, n);
}